// Round 7
// baseline (311.588 us; speedup 1.0000x reference)
//
#include <hip/hip_runtime.h>
#include <cmath>

// ---------------------------------------------------------------------------
// PatchTST encoder layer w/ p-RoPE, MI355X (gfx950).  Round 7:
//  - flash reverted to round-5 winner (16x16x32, 256-thr, 65.6us measured;
//    round-6 32x32 S^T variant regressed: 5.5M bank conflicts + 6 waves/CU).
//  - FFN2: 128x128-tile split-K=4 (grid 6x32x4) with fp32 unsafeAtomicAdd
//    into memset-zeroed d_out; z==0 split folds bias+residual.  Replaces the
//    64x64-tile version whose K=3072 refetch was ~600MB.
//  - all GEMMs: L2-locality block swizzle (bx=id/GY, by=id%GY) -> B-panel
//    shared by 32 consecutive blocks, per-XCD A-tile set (~800KB) L2-resident.
// Fragment layouts (verified): A[m=l15][k=quad*8+j]; B from Bt rows;
// C/D col=l15,row=quad*4+reg. XOR-swizzled LDS, async global_load_lds.
// ---------------------------------------------------------------------------

typedef __bf16 bf16_t;
typedef bf16_t bf16x8 __attribute__((ext_vector_type(8)));
typedef float floatx4 __attribute__((ext_vector_type(4)));

#define MFMA(a, b, c) __builtin_amdgcn_mfma_f32_16x16x32_bf16((a), (b), (c), 0, 0, 0)
#define LOG2E 1.44269504088896340736f

__device__ __forceinline__ bf16_t f2bf(float f) { return (bf16_t)f; }

__device__ __forceinline__ void g2l16(const void* g, void* l) {
  __builtin_amdgcn_global_load_lds(
      (const __attribute__((address_space(1))) unsigned int*)g,
      (__attribute__((address_space(3))) unsigned int*)l, 16, 0, 0);
}

__device__ __forceinline__ void lds_fence() {
  asm volatile("s_waitcnt lgkmcnt(0)" ::: "memory");
}

// ---------------------------------------------------------------------------
// k_prep: all weight transposes (fp32 [R][C] -> bf16 [C][R]) + LN1, one grid.
// ---------------------------------------------------------------------------
struct PrepP {
  const float *wq, *wk, *wv, *wo, *w1, *w2;
  bf16_t *wqkvT, *woT, *w1T, *w2T;
  const float *hs, *g1, *be1;
  bf16_t* ni;
};

__global__ __launch_bounds__(256) void k_prep(PrepP p) {
  __shared__ float shm[32 * 33];
  const int bid = blockIdx.x;
  if (bid < 6912) {
    const float* in;
    bf16_t* out;
    int R, C, tx, ty;
    if (bid < 2304) {
      int m = bid / 576, lo = bid % 576;
      in = (m == 0) ? p.wq : (m == 1) ? p.wk : (m == 2) ? p.wv : p.wo;
      out = (m < 3) ? p.wqkvT + (size_t)m * 768 * 768 : p.woT;
      R = 768; C = 768; tx = lo % 24; ty = lo / 24;
    } else if (bid < 4608) {
      int lo = bid - 2304;
      in = p.w1; out = p.w1T; R = 768; C = 3072; tx = lo % 96; ty = lo / 96;
    } else {
      int lo = bid - 4608;
      in = p.w2; out = p.w2T; R = 3072; C = 768; tx = lo % 24; ty = lo / 24;
    }
    const int c0 = tx * 32, r0 = ty * 32;
    const int lx = threadIdx.x & 31, ly = threadIdx.x >> 5;
#pragma unroll
    for (int p4 = 0; p4 < 4; p4++) {
      int r = ly + p4 * 8;
      shm[r * 33 + lx] = in[(size_t)(r0 + r) * C + c0 + lx];
    }
    __syncthreads();
#pragma unroll
    for (int p4 = 0; p4 < 4; p4++) {
      int r = ly + p4 * 8;
      out[(size_t)(c0 + r) * R + r0 + lx] = f2bf(shm[lx * 33 + r]);
    }
  } else {
    const int row = bid - 6912;
    const float* xr = p.hs + (size_t)row * 768;
    const int t = threadIdx.x;
    float v0 = xr[t], v1 = xr[t + 256], v2 = xr[t + 512];
    float s = v0 + v1 + v2;
    float s2 = v0 * v0 + v1 * v1 + v2 * v2;
#pragma unroll
    for (int off = 32; off; off >>= 1) {
      s += __shfl_xor(s, off);
      s2 += __shfl_xor(s2, off);
    }
    const int w = t >> 6;
    if ((t & 63) == 0) { shm[w] = s; shm[4 + w] = s2; }
    __syncthreads();
    s = shm[0] + shm[1] + shm[2] + shm[3];
    s2 = shm[4] + shm[5] + shm[6] + shm[7];
    const float mu = s * (1.0f / 768.0f);
    const float var = s2 * (1.0f / 768.0f) - mu * mu;
    const float rstd = rsqrtf(var + 1e-5f);
    bf16_t* orow = p.ni + (size_t)row * 768;
    orow[t]       = f2bf((v0 - mu) * rstd * p.g1[t]       + p.be1[t]);
    orow[t + 256] = f2bf((v1 - mu) * rstd * p.g1[t + 256] + p.be1[t + 256]);
    orow[t + 512] = f2bf((v2 - mu) * rstd * p.g1[t + 512] + p.be1[t + 512]);
  }
}

// ---------------------------------------------------------------------------
// LayerNorm (LN3): fp32 in -> bf16 out, one block per row.
// ---------------------------------------------------------------------------
__global__ __launch_bounds__(256) void k_layernorm(
    const float* __restrict__ x, const float* __restrict__ g,
    const float* __restrict__ b, bf16_t* __restrict__ out) {
  const int row = blockIdx.x;
  const float* xr = x + (size_t)row * 768;
  const int t = threadIdx.x;
  float v0 = xr[t], v1 = xr[t + 256], v2 = xr[t + 512];
  float s = v0 + v1 + v2;
  float s2 = v0 * v0 + v1 * v1 + v2 * v2;
#pragma unroll
  for (int off = 32; off; off >>= 1) {
    s += __shfl_xor(s, off);
    s2 += __shfl_xor(s2, off);
  }
  __shared__ float ra[4], rb[4];
  const int w = t >> 6;
  if ((t & 63) == 0) { ra[w] = s; rb[w] = s2; }
  __syncthreads();
  s = ra[0] + ra[1] + ra[2] + ra[3];
  s2 = rb[0] + rb[1] + rb[2] + rb[3];
  const float mu = s * (1.0f / 768.0f);
  const float var = s2 * (1.0f / 768.0f) - mu * mu;
  const float rstd = rsqrtf(var + 1e-5f);
  bf16_t* orow = out + (size_t)row * 768;
  orow[t]       = f2bf((v0 - mu) * rstd * g[t]       + b[t]);
  orow[t + 256] = f2bf((v1 - mu) * rstd * g[t + 256] + b[t + 256]);
  orow[t + 512] = f2bf((v2 - mu) * rstd * g[t + 512] + b[t + 512]);
}

// ---------------------------------------------------------------------------
// 128x128-tile bf16 MFMA GEMM (QKV mode 0, FFN1 mode 2). m97 structure.
// L2-locality swizzle: bx=id/GY, by=id%GY.
// ---------------------------------------------------------------------------
struct GemmP {
  const bf16_t* A;
  const bf16_t* Bt;
  int M, N, K, mode;
  const float* bias0;
  const float* bias1;
  const float* bias2;
  float* outF;
  bf16_t* outB0;
  bf16_t* outB1;
  bf16_t* outB2;
};

__global__ __launch_bounds__(256, 3) void k_gemm(GemmP p) {
  __shared__ bf16_t lds[18432];  // 36 KiB: lA@0[8192], lB@8192[8192] + scratch
  const int tid = threadIdx.x;
  const int lane = tid & 63, wave = tid >> 6;
  const int quad = lane >> 4, l15 = lane & 15;
  const int wm = (wave >> 1) * 64, wn = (wave & 1) * 64;
  const int id = blockIdx.y * gridDim.x + blockIdx.x;
  const int bx = id / gridDim.y, by = id % gridDim.y;
  const int m0 = by * 128, n0 = bx * 128;

  const char* gA[4];
  const char* gB[4];
#pragma unroll
  for (int pp = 0; pp < 4; pp++) {
    int slot = wave * 256 + pp * 64 + lane;
    int r = slot >> 3;
    int c8 = ((slot & 7) ^ (r & 7)) << 3;
    gA[pp] = (const char*)(p.A + (size_t)(m0 + r) * p.K + c8);
    gB[pp] = (const char*)(p.Bt + (size_t)(n0 + r) * p.K + c8);
  }

  int offA[4], offB[4];
#pragma unroll
  for (int i = 0; i < 4; i++) {
    int ra = wm + i * 16 + l15;
    offA[i] = ra * 64 + ((quad * 8) ^ ((ra & 7) << 3));
    int rb = wn + i * 16 + l15;
    offB[i] = rb * 64 + ((quad * 8) ^ ((rb & 7) << 3));
  }

  const floatx4 z4 = {0.f, 0.f, 0.f, 0.f};
  floatx4 acc[4][4];
#pragma unroll
  for (int i = 0; i < 4; i++)
#pragma unroll
    for (int j = 0; j < 4; j++) acc[i][j] = z4;

  const int KT = p.K >> 6;
  bf16_t* Ad = lds + wave * 2048;
  bf16_t* Bd = lds + 8192 + wave * 2048;

  for (int kt = 0; kt < KT; kt++) {
    const size_t kb = (size_t)kt * 128;  // bytes
#pragma unroll
    for (int pp = 0; pp < 4; pp++) {
      g2l16(gA[pp] + kb, Ad + pp * 512);
      g2l16(gB[pp] + kb, Bd + pp * 512);
    }
    __syncthreads();
#pragma unroll
    for (int ks = 0; ks < 2; ks++) {
      bf16x8 af[4], bfr[4];
#pragma unroll
      for (int i = 0; i < 4; i++) {
        af[i] = *(const bf16x8*)(lds + (offA[i] ^ (ks * 32)));
        bfr[i] = *(const bf16x8*)(lds + 8192 + (offB[i] ^ (ks * 32)));
      }
#pragma unroll
      for (int i = 0; i < 4; i++)
#pragma unroll
        for (int j = 0; j < 4; j++) acc[i][j] = MFMA(af[i], bfr[j], acc[i][j]);
    }
    __syncthreads();
  }

  char* scr = (char*)lds + wave * 9216;

  if (p.mode == 0) {
    const int gnw = n0 + wn;
    const int region = gnw / 768;  // block-uniform
    const int rem = gnw - region * 768;
    const int h = rem >> 6;
    const int b = (m0 + wm) >> 11;
    const int t0 = (m0 + wm) & 2047;
    const float* bias = (region == 0) ? p.bias0 : (region == 1 ? p.bias1 : p.bias2);
    float bb[4];
#pragma unroll
    for (int j = 0; j < 4; j++) bb[j] = bias[h * 64 + j * 16 + l15];
    bf16_t* sb = (bf16_t*)scr;  // [64][72]
    if (region < 2) {
      const float scale = (region == 0) ? 0.125f * LOG2E : 1.0f;
      const float inv_ts = exp2f(-(float)l15 * (13.287712379549449f / 32.0f));
#pragma unroll
      for (int i = 0; i < 4; i++) {
#pragma unroll
        for (int reg = 0; reg < 4; reg++) {
          int tl = i * 16 + quad * 4 + reg;
          float sn, cs;
          __sincosf((float)(t0 + tl) * inv_ts, &sn, &cs);
          float v0 = (acc[i][0][reg] + bb[0]) * scale;
          float v1 = (acc[i][1][reg] + bb[1]) * scale;
          float v2 = (acc[i][2][reg] + bb[2]) * scale;
          float v3 = (acc[i][3][reg] + bb[3]) * scale;
          sb[tl * 72 + l15]      = f2bf(v0 * cs - v2 * sn);
          sb[tl * 72 + 16 + l15] = f2bf(v1);
          sb[tl * 72 + 32 + l15] = f2bf(v2 * cs + v0 * sn);
          sb[tl * 72 + 48 + l15] = f2bf(v3);
        }
      }
      __syncthreads();
      bf16_t* outp = (region == 0) ? p.outB0 : p.outB1;
      bf16_t* ob = outp + (((size_t)(b * 12 + h) * 2048 + t0) << 6);
#pragma unroll
      for (int pp = 0; pp < 8; pp++) {
        int row = pp * 8 + (lane >> 3), ch = (lane & 7) << 3;
        *(bf16x8*)(ob + row * 64 + ch) = *(const bf16x8*)&sb[row * 72 + ch];
      }
    } else {
#pragma unroll
      for (int i = 0; i < 4; i++)
#pragma unroll
        for (int j = 0; j < 4; j++)
#pragma unroll
          for (int reg = 0; reg < 4; reg++)
            sb[(j * 16 + l15) * 72 + i * 16 + quad * 4 + reg] =
                f2bf(acc[i][j][reg] + bb[j]);
      __syncthreads();
      bf16_t* ob = p.outB2 + (((size_t)(b * 12 + h)) << 17) + t0;
#pragma unroll
      for (int pp = 0; pp < 8; pp++) {
        int d = pp * 8 + (lane >> 3), ch = (lane & 7) << 3;
        *(bf16x8*)(ob + (size_t)d * 2048 + ch) = *(const bf16x8*)&sb[d * 72 + ch];
      }
    }
  } else {  // mode 2: FFN1 + exact GELU -> bf16
    bf16_t* sb = (bf16_t*)scr;  // [64][72]
    float bb[4];
#pragma unroll
    for (int j = 0; j < 4; j++) bb[j] = p.bias0[n0 + wn + j * 16 + l15];
#pragma unroll
    for (int i = 0; i < 4; i++)
#pragma unroll
      for (int j = 0; j < 4; j++)
#pragma unroll
        for (int reg = 0; reg < 4; reg++) {
          int tl = i * 16 + quad * 4 + reg;
          float x = acc[i][j][reg] + bb[j];
          float gv = 0.5f * x * (1.0f + erff(x * 0.70710678118654752f));
          sb[tl * 72 + j * 16 + l15] = f2bf(gv);
        }
    __syncthreads();
#pragma unroll
    for (int pp = 0; pp < 8; pp++) {
      int row = pp * 8 + (lane >> 3), ch = (lane & 7) << 3;
      *(bf16x8*)(p.outB0 + (size_t)(m0 + wm + row) * p.N + n0 + wn + ch) =
          *(const bf16x8*)&sb[row * 72 + ch];
    }
  }
}

// ---------------------------------------------------------------------------
// 64x64-tile GEMM (WO): fp32 out = acc + bias + resid. Swizzled block map.
// ---------------------------------------------------------------------------
__global__ __launch_bounds__(256, 4) void k_gemm64(
    const bf16_t* __restrict__ A, const bf16_t* __restrict__ Bt, int N, int K,
    const float* __restrict__ bias, const float* __restrict__ resid,
    float* __restrict__ outF) {
  __shared__ bf16_t lds[16384];  // 32 KiB
  const int tid = threadIdx.x;
  const int lane = tid & 63, wave = tid >> 6;
  const int quad = lane >> 4, l15 = lane & 15;
  const int wm = (wave >> 1) * 32, wn = (wave & 1) * 32;
  const int id = blockIdx.y * gridDim.x + blockIdx.x;
  const int bx = id / gridDim.y, by = id % gridDim.y;
  const int m0 = by * 64, n0 = bx * 64;

  const char* gA[4];
  const char* gB[4];
#pragma unroll
  for (int pp = 0; pp < 4; pp++) {
    int slot = wave * 256 + pp * 64 + lane;
    int r = slot >> 4;
    int c = ((slot & 15) ^ (r & 7)) << 3;  // elems
    gA[pp] = (const char*)(A + (size_t)(m0 + r) * K + c);
    gB[pp] = (const char*)(Bt + (size_t)(n0 + r) * K + c);
  }

  const floatx4 z4 = {0.f, 0.f, 0.f, 0.f};
  floatx4 acc[2][2];
#pragma unroll
  for (int i = 0; i < 2; i++)
#pragma unroll
    for (int j = 0; j < 2; j++) acc[i][j] = z4;

  const int KT = K >> 7;
  bf16_t* Ad = lds + wave * 2048;
  bf16_t* Bd = lds + 8192 + wave * 2048;

  for (int kt = 0; kt < KT; kt++) {
    const size_t kb = (size_t)kt * 256;  // bytes (128 elems)
#pragma unroll
    for (int pp = 0; pp < 4; pp++) {
      g2l16(gA[pp] + kb, Ad + pp * 512);
      g2l16(gB[pp] + kb, Bd + pp * 512);
    }
    __syncthreads();
#pragma unroll
    for (int ks = 0; ks < 4; ks++) {
      bf16x8 af[2], bfr[2];
#pragma unroll
      for (int i = 0; i < 2; i++) {
        int ra = wm + i * 16 + l15;
        af[i] = *(const bf16x8*)(lds + ra * 128 +
                                 (((ks * 4 + quad) ^ (ra & 7)) << 3));
        int rb = wn + i * 16 + l15;
        bfr[i] = *(const bf16x8*)(lds + 8192 + rb * 128 +
                                  (((ks * 4 + quad) ^ (rb & 7)) << 3));
      }
#pragma unroll
      for (int i = 0; i < 2; i++)
#pragma unroll
        for (int j = 0; j < 2; j++) acc[i][j] = MFMA(af[i], bfr[j], acc[i][j]);
    }
    __syncthreads();
  }

  float* s4 = (float*)lds + wave * 1024;
#pragma unroll
  for (int i = 0; i < 2; i++)
#pragma unroll
    for (int j = 0; j < 2; j++)
#pragma unroll
      for (int reg = 0; reg < 4; reg++)
        s4[(i * 16 + quad * 4 + reg) * 32 + j * 16 + l15] = acc[i][j][reg];
  __syncthreads();
#pragma unroll
  for (int pp = 0; pp < 4; pp++) {
    int row = pp * 8 + (lane >> 3);
    int c4 = (lane & 7) * 4;
    floatx4 v = *(const floatx4*)&s4[row * 32 + c4];
    size_t goff = (size_t)(m0 + wm + row) * N + n0 + wn + c4;
    floatx4 rv = *(const floatx4*)(resid + goff);
    floatx4 bv = *(const floatx4*)(bias + n0 + wn + c4);
    *(floatx4*)(outF + goff) = v + rv + bv;
  }
}

// ---------------------------------------------------------------------------
// Split-K 128x128-tile GEMM (FFN2): grid (N/128, M/128, S). Each split does
// K-chunk `chunk`; epilogue unsafeAtomicAdd into zeroed outF; z==0 adds
// bias + residual. Swizzled (bx,by) within each z-slice.
// ---------------------------------------------------------------------------
__global__ __launch_bounds__(256, 3) void k_gemm_sk(
    const bf16_t* __restrict__ A, const bf16_t* __restrict__ Bt, int N, int K,
    int chunk, const float* __restrict__ bias, const float* __restrict__ resid,
    float* __restrict__ outF) {
  __shared__ bf16_t lds[16384];  // 32 KiB staging only
  const int tid = threadIdx.x;
  const int lane = tid & 63, wave = tid >> 6;
  const int quad = lane >> 4, l15 = lane & 15;
  const int wm = (wave >> 1) * 64, wn = (wave & 1) * 64;
  const int id = blockIdx.y * gridDim.x + blockIdx.x;
  const int bx = id / gridDim.y, by = id % gridDim.y;
  const int m0 = by * 128, n0 = bx * 128;
  const int k0 = blockIdx.z * chunk;

  const char* gA[4];
  const char* gB[4];
#pragma unroll
  for (int pp = 0; pp < 4; pp++) {
    int slot = wave * 256 + pp * 64 + lane;
    int r = slot >> 3;
    int c8 = ((slot & 7) ^ (r & 7)) << 3;
    gA[pp] = (const char*)(A + (size_t)(m0 + r) * K + k0 + c8);
    gB[pp] = (const char*)(Bt + (size_t)(n0 + r) * K + k0 + c8);
  }

  int offA[4], offB[4];
#pragma unroll
  for (int i = 0; i < 4; i++) {
    int ra = wm + i * 16 + l15;
    offA[i] = ra * 64 + ((quad * 8) ^ ((ra & 7) << 3));
    int rb = wn + i * 16 + l15;
    offB[i] = rb * 64 + ((quad * 8) ^ ((rb & 7) << 3));
  }

  const floatx4 z4 = {0.f, 0.f, 0.f, 0.f};
  floatx4 acc[4][4];
#pragma unroll
  for (int i = 0; i < 4; i++)
#pragma unroll
    for (int j = 0; j < 4; j++) acc[i][j] = z4;

  const int KT = chunk >> 6;
  bf16_t* Ad = lds + wave * 2048;
  bf16_t* Bd = lds + 8192 + wave * 2048;

  for (int kt = 0; kt < KT; kt++) {
    const size_t kb = (size_t)kt * 128;  // bytes
#pragma unroll
    for (int pp = 0; pp < 4; pp++) {
      g2l16(gA[pp] + kb, Ad + pp * 512);
      g2l16(gB[pp] + kb, Bd + pp * 512);
    }
    __syncthreads();
#pragma unroll
    for (int ks = 0; ks < 2; ks++) {
      bf16x8 af[4], bfr[4];
#pragma unroll
      for (int i = 0; i < 4; i++) {
        af[i] = *(const bf16x8*)(lds + (offA[i] ^ (ks * 32)));
        bfr[i] = *(const bf16x8*)(lds + 8192 + (offB[i] ^ (ks * 32)));
      }
#pragma unroll
      for (int i = 0; i < 4; i++)
#pragma unroll
        for (int j = 0; j < 4; j++) acc[i][j] = MFMA(af[i], bfr[j], acc[i][j]);
    }
    __syncthreads();
  }

  // epilogue: atomic accumulate (order-independent across splits)
  const bool first = (blockIdx.z == 0);
#pragma unroll
  for (int i = 0; i < 4; i++)
#pragma unroll
    for (int j = 0; j < 4; j++)
#pragma unroll
      for (int reg = 0; reg < 4; reg++) {
        int row = m0 + wm + i * 16 + quad * 4 + reg;
        int col = n0 + wn + j * 16 + l15;
        size_t goff = (size_t)row * N + col;
        float v = acc[i][j][reg];
        if (first) v += bias[col] + resid[goff];
        unsafeAtomicAdd(outF + goff, v);
      }
}

// ---------------------------------------------------------------------------
// Flash attention (round-5 winner): 16x16x32, exp2-domain, no max sub,
// tile-uniform bias in exp2 arg, async dbuf, 1 barrier/iter, kv-tile 64.
// ---------------------------------------------------------------------------
__global__ __launch_bounds__(256, 3) void k_flash(
    const bf16_t* __restrict__ qh, const bf16_t* __restrict__ kh,
    const bf16_t* __restrict__ vt, const float* __restrict__ ab,
    bf16_t* __restrict__ attnA) {
  __shared__ bf16_t sm[20480];  // 40 KiB
  bf16_t* lK = sm;              // [2][4096]
  bf16_t* lV = sm + 8192;       // [2][4096]
  bf16_t* lP = sm + 16384;      // [4][1024] wave-private

  const int tid = threadIdx.x, lane = tid & 63, wave = tid >> 6;
  const int quad = lane >> 4, l15 = lane & 15;
  const int qtile = blockIdx.x, bh = blockIdx.y;
  const int h = bh % 12, bq = bh / 12;
  const int qr0 = qtile * 64 + wave * 16;

  const bf16_t* Qb = qh + (size_t)bh * 2048 * 64;
  const bf16_t* Kb = kh + (size_t)bh * 2048 * 64;
  const bf16_t* Vb = vt + (size_t)bh * 64 * 2048;

  const char* gK[2];
  const char* gV[2];
#pragma unroll
  for (int pp = 0; pp < 2; pp++) {
    int slot = wave * 128 + pp * 64 + lane;
    int r = slot >> 3;
    int c8 = ((slot & 7) ^ (r & 7)) << 3;
    gK[pp] = (const char*)(Kb + r * 64 + c8);
    gV[pp] = (const char*)(Vb + (size_t)r * 2048 + c8);
  }

  bf16x8 qf[2];
#pragma unroll
  for (int ks = 0; ks < 2; ks++)
    qf[ks] = *(const bf16x8*)(Qb + (size_t)(qr0 + l15) * 64 + ks * 32 + quad * 8);

  int offK[4];
#pragma unroll
  for (int t4 = 0; t4 < 4; t4++) {
    int sr = t4 * 16 + l15;
    offK[t4] = sr * 64 + ((quad * 8) ^ ((sr & 7) << 3));
  }
  const int offP = l15 * 64 + ((quad * 8) ^ ((l15 & 7) << 3));

  const floatx4 z4 = {0.f, 0.f, 0.f, 0.f};
  float l_all[4] = {0.f, 0.f, 0.f, 0.f};
  floatx4 oacc[4];
#pragma unroll
  for (int dt = 0; dt < 4; dt++) oacc[dt] = z4;

  const float bc_same = ab[h * 2] * LOG2E;
  const float bc_diff = ab[h * 2 + 1] * LOG2E;
  const int myv = qtile >> 1;

  {
    bf16_t* K0 = lK + wave * 1024;
    bf16_t* V0 = lV + wave * 1024;
#pragma unroll
    for (int pp = 0; pp < 2; pp++) {
      g2l16(gK[pp], K0 + pp * 512);
      g2l16(gV[pp], V0 + pp * 512);
    }
  }
  __syncthreads();

  for (int kv = 0; kv < 32; kv++) {
    const int cur = kv & 1;
    if (kv + 1 < 32) {
      bf16_t* K1 = lK + (cur ^ 1) * 4096 + wave * 1024;
      bf16_t* V1 = lV + (cur ^ 1) * 4096 + wave * 1024;
      const size_t kb = (size_t)(kv + 1) * 8192, vb = (size_t)(kv + 1) * 128;
#pragma unroll
      for (int pp = 0; pp < 2; pp++) {
        g2l16(gK[pp] + kb, K1 + pp * 512);
        g2l16(gV[pp] + vb, V1 + pp * 512);
      }
    }
    const bf16_t* K0 = lK + cur * 4096;
    const bf16_t* V0 = lV + cur * 4096;

    floatx4 sacc[4] = {z4, z4, z4, z4};
#pragma unroll
    for (int ks = 0; ks < 2; ks++)
#pragma unroll
      for (int ct = 0; ct < 4; ct++)
        sacc[ct] = MFMA(qf[ks], *(const bf16x8*)(K0 + (offK[ct] ^ (ks * 32))),
                        sacc[ct]);

    const float bc = ((kv >> 1) == myv) ? bc_same : bc_diff;
#pragma unroll
    for (int ct = 0; ct < 4; ct++)
#pragma unroll
      for (int reg = 0; reg < 4; reg++) {
        float pv = exp2f(sacc[ct][reg] + bc);
        sacc[ct][reg] = pv;
        l_all[reg] += pv;
      }

    bf16_t* myP = lP + wave * 1024;
#pragma unroll
    for (int ct = 0; ct < 4; ct++)
#pragma unroll
      for (int reg = 0; reg < 4; reg++) {
        int r = quad * 4 + reg, s = ct * 16 + l15;
        myP[r * 64 + (((s >> 3) ^ (r & 7)) << 3) + (s & 7)] =
            f2bf(sacc[ct][reg]);
      }
    lds_fence();

#pragma unroll
    for (int ks = 0; ks < 2; ks++) {
      bf16x8 pf = *(const bf16x8*)(myP + (offP ^ (ks * 32)));
#pragma unroll
      for (int dt = 0; dt < 4; dt++)
        oacc[dt] = MFMA(pf, *(const bf16x8*)(V0 + (offK[dt] ^ (ks * 32))),
                        oacc[dt]);
    }
    __syncthreads();
  }

  float inv_l[4];
#pragma unroll
  for (int reg = 0; reg < 4; reg++) {
    float la = l_all[reg];
    la += __shfl_xor(la, 1); la += __shfl_xor(la, 2);
    la += __shfl_xor(la, 4); la += __shfl_xor(la, 8);
    inv_l[reg] = 1.0f / la;
  }

  bf16_t* myP = lP + wave * 1024;
#pragma unroll
  for (int dt = 0; dt < 4; dt++)
#pragma unroll
    for (int reg = 0; reg < 4; reg++)
      myP[(quad * 4 + reg) * 64 + dt * 16 + l15] =
          f2bf(oacc[dt][reg] * inv_l[reg]);
  __syncthreads();
#pragma unroll
  for (int pp = 0; pp < 2; pp++) {
    int row = pp * 8 + (lane >> 3), ch = (lane & 7) << 3;
    *(bf16x8*)(attnA + ((size_t)(bq * 2048 + qr0 + row)) * 768 + h * 64 + ch) =
        *(const bf16x8*)&myP[row * 64 + ch];
  }
}

// ---------------------------------------------------------------------------
extern "C" void kernel_launch(void* const* d_in, const int* in_sizes, int n_in,
                              void* d_out, int out_size, void* d_ws,
                              size_t ws_size, hipStream_t stream) {
  const float* hs  = (const float*)d_in[0];
  const float* wq  = (const float*)d_in[1];
  const float* bq  = (const float*)d_in[2];
  const float* wk  = (const float*)d_in[3];
  const float* bk  = (const float*)d_in[4];
  const float* wv  = (const float*)d_in[5];
  const float* bv  = (const float*)d_in[6];
  const float* wo  = (const float*)d_in[7];
  const float* bo  = (const float*)d_in[8];
  const float* ab  = (const float*)d_in[9];
  const float* g1  = (const float*)d_in[10];
  const float* be1 = (const float*)d_in[11];
  const float* g3  = (const float*)d_in[12];
  const float* be3 = (const float*)d_in[13];
  const float* w1  = (const float*)d_in[14];
  const float* b1  = (const float*)d_in[15];
  const float* w2  = (const float*)d_in[16];
  const float* b2  = (const float*)d_in[17];

  char* ws = (char*)d_ws;
  size_t off = 0;
  auto alloc = [&](size_t bytes) -> void* {
    void* p = ws + off;
    off += (bytes + 255) & ~(size_t)255;
    return p;
  };
  bf16_t* wqkvT = (bf16_t*)alloc((size_t)2304 * 768 * 2);
  bf16_t* woT   = (bf16_t*)alloc((size_t)768 * 768 * 2);
  bf16_t* w1T   = (bf16_t*)alloc((size_t)3072 * 768 * 2);
  bf16_t* w2T   = (bf16_t*)alloc((size_t)768 * 3072 * 2);
  bf16_t* ni    = (bf16_t*)alloc((size_t)4096 * 768 * 2);
  bf16_t* qhB   = (bf16_t*)alloc((size_t)24 * 2048 * 64 * 2);
  bf16_t* khB   = (bf16_t*)alloc((size_t)24 * 2048 * 64 * 2);
  bf16_t* vtB   = (bf16_t*)alloc((size_t)24 * 64 * 2048 * 2);
  bf16_t* attnA = (bf16_t*)alloc((size_t)4096 * 768 * 2);
  float*  resid1 = (float*)alloc((size_t)4096 * 768 * 4);
  bf16_t* ffn1o = qhB;  // overlay: q/k/v/attn region dead by FFN1 time

  // zero d_out early (FFN2 split-K accumulates atomically into it)
  hipMemsetAsync(d_out, 0, (size_t)4096 * 768 * 4, stream);

  // prep: all transposes + LN1, one dispatch
  PrepP pp = {wq, wk, wv, wo, w1, w2, wqkvT, woT, w1T, w2T, hs, g1, be1, ni};
  k_prep<<<11008, 256, 0, stream>>>(pp);

  // QKV (fused, N=2304): bias, q*0.125*log2e, p-RoPE, head-layout scatter
  GemmP gqkv = {ni, wqkvT, 4096, 2304, 768, 0,
                bq, bk, bv, nullptr, qhB, khB, vtB};
  k_gemm<<<dim3(18, 32), 256, 0, stream>>>(gqkv);

  // flash attention (round-5 config)
  k_flash<<<dim3(32, 24), 256, 0, stream>>>(qhB, khB, vtB, ab, attnA);

  // attn @ wo + bo + residual(hidden) -> resid1 (fp32)
  k_gemm64<<<dim3(12, 64), 256, 0, stream>>>(attnA, woT, 768, 768, bo, hs,
                                             resid1);

  // LN3
  k_layernorm<<<4096, 256, 0, stream>>>(resid1, g3, be3, ni);

  // FFN1 + exact GELU -> bf16
  GemmP gf1 = {ni, w1T, 4096, 3072, 768, 2,
               b1, nullptr, nullptr, nullptr, ffn1o, nullptr, nullptr};
  k_gemm<<<dim3(24, 32), 256, 0, stream>>>(gf1);

  // FFN2 split-K=4 + b2 + residual -> d_out (atomic accumulate)
  k_gemm_sk<<<dim3(6, 32, 4), 256, 0, stream>>>(ffn1o, w2T, 768, 3072, 768,
                                                b2, resid1, (float*)d_out);
}

// Round 8
// 287.693 us; speedup vs baseline: 1.0831x; 1.0831x over previous
//
#include <hip/hip_runtime.h>
#include <cmath>

// ---------------------------------------------------------------------------
// PatchTST encoder layer w/ p-RoPE, MI355X (gfx950).  Round 8:
//  - GEMMs/prep/LN reverted to round-5 exact state (split-K + swizzle of r7
//    both reverted; FFN2 back to k_gemm64).
//  - flash v3: BARRIER-FREE wave-private pipeline.  s-dimension split across
//    the 4 waves (16 s/wave/iter, kv-tile 64).  Each wave DMAs its own K/V
//    slice into private LDS (double-buffered), computes S[64q][16s] with Q
//    held in registers, exp2 -> private P, and PV once per iter-PAIR (s=32 =
//    one MFMA K-dim; variate bias is pair-uniform).  Zero __syncthreads in
//    the loop; a single constant `s_waitcnt vmcnt(4)` per iter (uniform via
//    wraparound issue).  Cross-wave O/l reduction once at the end.
// Fragment layouts (verified, guide §3, 16x16x32 only):
//   A[m=lane&15][k=quad*8+j]; B[k=quad*8+j][n=lane&15];
//   C/D col=lane&15, row=quad*4+reg.
// ---------------------------------------------------------------------------

typedef __bf16 bf16_t;
typedef bf16_t bf16x8 __attribute__((ext_vector_type(8)));
typedef float floatx4 __attribute__((ext_vector_type(4)));

#define MFMA(a, b, c) __builtin_amdgcn_mfma_f32_16x16x32_bf16((a), (b), (c), 0, 0, 0)
#define LOG2E 1.44269504088896340736f

__device__ __forceinline__ bf16_t f2bf(float f) { return (bf16_t)f; }

__device__ __forceinline__ void g2l16(const void* g, void* l) {
  __builtin_amdgcn_global_load_lds(
      (const __attribute__((address_space(1))) unsigned int*)g,
      (__attribute__((address_space(3))) unsigned int*)l, 16, 0, 0);
}

__device__ __forceinline__ void lds_fence() {
  asm volatile("s_waitcnt lgkmcnt(0)" ::: "memory");
}
__device__ __forceinline__ void wait_vm4() {
  asm volatile("s_waitcnt vmcnt(4)" ::: "memory");
}

// ---------------------------------------------------------------------------
// k_prep: all weight transposes (fp32 [R][C] -> bf16 [C][R]) + LN1, one grid.
// ---------------------------------------------------------------------------
struct PrepP {
  const float *wq, *wk, *wv, *wo, *w1, *w2;
  bf16_t *wqkvT, *woT, *w1T, *w2T;
  const float *hs, *g1, *be1;
  bf16_t* ni;
};

__global__ __launch_bounds__(256) void k_prep(PrepP p) {
  __shared__ float shm[32 * 33];
  const int bid = blockIdx.x;
  if (bid < 6912) {
    const float* in;
    bf16_t* out;
    int R, C, tx, ty;
    if (bid < 2304) {
      int m = bid / 576, lo = bid % 576;
      in = (m == 0) ? p.wq : (m == 1) ? p.wk : (m == 2) ? p.wv : p.wo;
      out = (m < 3) ? p.wqkvT + (size_t)m * 768 * 768 : p.woT;
      R = 768; C = 768; tx = lo % 24; ty = lo / 24;
    } else if (bid < 4608) {
      int lo = bid - 2304;
      in = p.w1; out = p.w1T; R = 768; C = 3072; tx = lo % 96; ty = lo / 96;
    } else {
      int lo = bid - 4608;
      in = p.w2; out = p.w2T; R = 3072; C = 768; tx = lo % 24; ty = lo / 24;
    }
    const int c0 = tx * 32, r0 = ty * 32;
    const int lx = threadIdx.x & 31, ly = threadIdx.x >> 5;
#pragma unroll
    for (int p4 = 0; p4 < 4; p4++) {
      int r = ly + p4 * 8;
      shm[r * 33 + lx] = in[(size_t)(r0 + r) * C + c0 + lx];
    }
    __syncthreads();
#pragma unroll
    for (int p4 = 0; p4 < 4; p4++) {
      int r = ly + p4 * 8;
      out[(size_t)(c0 + r) * R + r0 + lx] = f2bf(shm[lx * 33 + r]);
    }
  } else {
    const int row = bid - 6912;
    const float* xr = p.hs + (size_t)row * 768;
    const int t = threadIdx.x;
    float v0 = xr[t], v1 = xr[t + 256], v2 = xr[t + 512];
    float s = v0 + v1 + v2;
    float s2 = v0 * v0 + v1 * v1 + v2 * v2;
#pragma unroll
    for (int off = 32; off; off >>= 1) {
      s += __shfl_xor(s, off);
      s2 += __shfl_xor(s2, off);
    }
    const int w = t >> 6;
    if ((t & 63) == 0) { shm[w] = s; shm[4 + w] = s2; }
    __syncthreads();
    s = shm[0] + shm[1] + shm[2] + shm[3];
    s2 = shm[4] + shm[5] + shm[6] + shm[7];
    const float mu = s * (1.0f / 768.0f);
    const float var = s2 * (1.0f / 768.0f) - mu * mu;
    const float rstd = rsqrtf(var + 1e-5f);
    bf16_t* orow = p.ni + (size_t)row * 768;
    orow[t]       = f2bf((v0 - mu) * rstd * p.g1[t]       + p.be1[t]);
    orow[t + 256] = f2bf((v1 - mu) * rstd * p.g1[t + 256] + p.be1[t + 256]);
    orow[t + 512] = f2bf((v2 - mu) * rstd * p.g1[t + 512] + p.be1[t + 512]);
  }
}

// ---------------------------------------------------------------------------
// LayerNorm (LN3): fp32 in -> bf16 out, one block per row.
// ---------------------------------------------------------------------------
__global__ __launch_bounds__(256) void k_layernorm(
    const float* __restrict__ x, const float* __restrict__ g,
    const float* __restrict__ b, bf16_t* __restrict__ out) {
  const int row = blockIdx.x;
  const float* xr = x + (size_t)row * 768;
  const int t = threadIdx.x;
  float v0 = xr[t], v1 = xr[t + 256], v2 = xr[t + 512];
  float s = v0 + v1 + v2;
  float s2 = v0 * v0 + v1 * v1 + v2 * v2;
#pragma unroll
  for (int off = 32; off; off >>= 1) {
    s += __shfl_xor(s, off);
    s2 += __shfl_xor(s2, off);
  }
  __shared__ float ra[4], rb[4];
  const int w = t >> 6;
  if ((t & 63) == 0) { ra[w] = s; rb[w] = s2; }
  __syncthreads();
  s = ra[0] + ra[1] + ra[2] + ra[3];
  s2 = rb[0] + rb[1] + rb[2] + rb[3];
  const float mu = s * (1.0f / 768.0f);
  const float var = s2 * (1.0f / 768.0f) - mu * mu;
  const float rstd = rsqrtf(var + 1e-5f);
  bf16_t* orow = out + (size_t)row * 768;
  orow[t]       = f2bf((v0 - mu) * rstd * g[t]       + b[t]);
  orow[t + 256] = f2bf((v1 - mu) * rstd * g[t + 256] + b[t + 256]);
  orow[t + 512] = f2bf((v2 - mu) * rstd * g[t + 512] + b[t + 512]);
}

// ---------------------------------------------------------------------------
// 128x128-tile bf16 MFMA GEMM (QKV mode 0, FFN1 mode 2). m97 structure (r5).
// ---------------------------------------------------------------------------
struct GemmP {
  const bf16_t* A;
  const bf16_t* Bt;
  int M, N, K, mode;
  const float* bias0;
  const float* bias1;
  const float* bias2;
  float* outF;
  bf16_t* outB0;
  bf16_t* outB1;
  bf16_t* outB2;
};

__global__ __launch_bounds__(256, 3) void k_gemm(GemmP p) {
  __shared__ bf16_t lds[18432];  // 36 KiB
  const int tid = threadIdx.x;
  const int lane = tid & 63, wave = tid >> 6;
  const int quad = lane >> 4, l15 = lane & 15;
  const int wm = (wave >> 1) * 64, wn = (wave & 1) * 64;
  const int m0 = blockIdx.y * 128, n0 = blockIdx.x * 128;

  const char* gA[4];
  const char* gB[4];
#pragma unroll
  for (int pp = 0; pp < 4; pp++) {
    int slot = wave * 256 + pp * 64 + lane;
    int r = slot >> 3;
    int c8 = ((slot & 7) ^ (r & 7)) << 3;
    gA[pp] = (const char*)(p.A + (size_t)(m0 + r) * p.K + c8);
    gB[pp] = (const char*)(p.Bt + (size_t)(n0 + r) * p.K + c8);
  }

  int offA[4], offB[4];
#pragma unroll
  for (int i = 0; i < 4; i++) {
    int ra = wm + i * 16 + l15;
    offA[i] = ra * 64 + ((quad * 8) ^ ((ra & 7) << 3));
    int rb = wn + i * 16 + l15;
    offB[i] = rb * 64 + ((quad * 8) ^ ((rb & 7) << 3));
  }

  const floatx4 z4 = {0.f, 0.f, 0.f, 0.f};
  floatx4 acc[4][4];
#pragma unroll
  for (int i = 0; i < 4; i++)
#pragma unroll
    for (int j = 0; j < 4; j++) acc[i][j] = z4;

  const int KT = p.K >> 6;
  bf16_t* Ad = lds + wave * 2048;
  bf16_t* Bd = lds + 8192 + wave * 2048;

  for (int kt = 0; kt < KT; kt++) {
    const size_t kb = (size_t)kt * 128;
#pragma unroll
    for (int pp = 0; pp < 4; pp++) {
      g2l16(gA[pp] + kb, Ad + pp * 512);
      g2l16(gB[pp] + kb, Bd + pp * 512);
    }
    __syncthreads();
#pragma unroll
    for (int ks = 0; ks < 2; ks++) {
      bf16x8 af[4], bfr[4];
#pragma unroll
      for (int i = 0; i < 4; i++) {
        af[i] = *(const bf16x8*)(lds + (offA[i] ^ (ks * 32)));
        bfr[i] = *(const bf16x8*)(lds + 8192 + (offB[i] ^ (ks * 32)));
      }
#pragma unroll
      for (int i = 0; i < 4; i++)
#pragma unroll
        for (int j = 0; j < 4; j++) acc[i][j] = MFMA(af[i], bfr[j], acc[i][j]);
    }
    __syncthreads();
  }

  char* scr = (char*)lds + wave * 9216;

  if (p.mode == 0) {
    const int gnw = n0 + wn;
    const int region = gnw / 768;  // block-uniform
    const int rem = gnw - region * 768;
    const int h = rem >> 6;
    const int b = (m0 + wm) >> 11;
    const int t0 = (m0 + wm) & 2047;
    const float* bias = (region == 0) ? p.bias0 : (region == 1 ? p.bias1 : p.bias2);
    float bb[4];
#pragma unroll
    for (int j = 0; j < 4; j++) bb[j] = bias[h * 64 + j * 16 + l15];
    bf16_t* sb = (bf16_t*)scr;  // [64][72]
    if (region < 2) {
      const float scale = (region == 0) ? 0.125f * LOG2E : 1.0f;
      const float inv_ts = exp2f(-(float)l15 * (13.287712379549449f / 32.0f));
#pragma unroll
      for (int i = 0; i < 4; i++) {
#pragma unroll
        for (int reg = 0; reg < 4; reg++) {
          int tl = i * 16 + quad * 4 + reg;
          float sn, cs;
          __sincosf((float)(t0 + tl) * inv_ts, &sn, &cs);
          float v0 = (acc[i][0][reg] + bb[0]) * scale;
          float v1 = (acc[i][1][reg] + bb[1]) * scale;
          float v2 = (acc[i][2][reg] + bb[2]) * scale;
          float v3 = (acc[i][3][reg] + bb[3]) * scale;
          sb[tl * 72 + l15]      = f2bf(v0 * cs - v2 * sn);
          sb[tl * 72 + 16 + l15] = f2bf(v1);
          sb[tl * 72 + 32 + l15] = f2bf(v2 * cs + v0 * sn);
          sb[tl * 72 + 48 + l15] = f2bf(v3);
        }
      }
      __syncthreads();
      bf16_t* outp = (region == 0) ? p.outB0 : p.outB1;
      bf16_t* ob = outp + (((size_t)(b * 12 + h) * 2048 + t0) << 6);
#pragma unroll
      for (int pp = 0; pp < 8; pp++) {
        int row = pp * 8 + (lane >> 3), ch = (lane & 7) << 3;
        *(bf16x8*)(ob + row * 64 + ch) = *(const bf16x8*)&sb[row * 72 + ch];
      }
    } else {
#pragma unroll
      for (int i = 0; i < 4; i++)
#pragma unroll
        for (int j = 0; j < 4; j++)
#pragma unroll
          for (int reg = 0; reg < 4; reg++)
            sb[(j * 16 + l15) * 72 + i * 16 + quad * 4 + reg] =
                f2bf(acc[i][j][reg] + bb[j]);
      __syncthreads();
      bf16_t* ob = p.outB2 + (((size_t)(b * 12 + h)) << 17) + t0;
#pragma unroll
      for (int pp = 0; pp < 8; pp++) {
        int d = pp * 8 + (lane >> 3), ch = (lane & 7) << 3;
        *(bf16x8*)(ob + (size_t)d * 2048 + ch) = *(const bf16x8*)&sb[d * 72 + ch];
      }
    }
  } else {  // mode 2: FFN1 + exact GELU -> bf16
    bf16_t* sb = (bf16_t*)scr;  // [64][72]
    float bb[4];
#pragma unroll
    for (int j = 0; j < 4; j++) bb[j] = p.bias0[n0 + wn + j * 16 + l15];
#pragma unroll
    for (int i = 0; i < 4; i++)
#pragma unroll
      for (int j = 0; j < 4; j++)
#pragma unroll
        for (int reg = 0; reg < 4; reg++) {
          int tl = i * 16 + quad * 4 + reg;
          float x = acc[i][j][reg] + bb[j];
          float gv = 0.5f * x * (1.0f + erff(x * 0.70710678118654752f));
          sb[tl * 72 + j * 16 + l15] = f2bf(gv);
        }
    __syncthreads();
#pragma unroll
    for (int pp = 0; pp < 8; pp++) {
      int row = pp * 8 + (lane >> 3), ch = (lane & 7) << 3;
      *(bf16x8*)(p.outB0 + (size_t)(m0 + wm + row) * p.N + n0 + wn + ch) =
          *(const bf16x8*)&sb[row * 72 + ch];
    }
  }
}

// ---------------------------------------------------------------------------
// 64x64-tile GEMM (WO, FFN2): fp32 out = acc + bias + resid.  (r5 version)
// ---------------------------------------------------------------------------
__global__ __launch_bounds__(256, 4) void k_gemm64(
    const bf16_t* __restrict__ A, const bf16_t* __restrict__ Bt, int N, int K,
    const float* __restrict__ bias, const float* __restrict__ resid,
    float* __restrict__ outF) {
  __shared__ bf16_t lds[16384];  // 32 KiB
  const int tid = threadIdx.x;
  const int lane = tid & 63, wave = tid >> 6;
  const int quad = lane >> 4, l15 = lane & 15;
  const int wm = (wave >> 1) * 32, wn = (wave & 1) * 32;
  const int m0 = blockIdx.y * 64, n0 = blockIdx.x * 64;

  const char* gA[4];
  const char* gB[4];
#pragma unroll
  for (int pp = 0; pp < 4; pp++) {
    int slot = wave * 256 + pp * 64 + lane;
    int r = slot >> 4;
    int c = ((slot & 15) ^ (r & 7)) << 3;  // elems
    gA[pp] = (const char*)(A + (size_t)(m0 + r) * K + c);
    gB[pp] = (const char*)(Bt + (size_t)(n0 + r) * K + c);
  }

  const floatx4 z4 = {0.f, 0.f, 0.f, 0.f};
  floatx4 acc[2][2];
#pragma unroll
  for (int i = 0; i < 2; i++)
#pragma unroll
    for (int j = 0; j < 2; j++) acc[i][j] = z4;

  const int KT = K >> 7;
  bf16_t* Ad = lds + wave * 2048;
  bf16_t* Bd = lds + 8192 + wave * 2048;

  for (int kt = 0; kt < KT; kt++) {
    const size_t kb = (size_t)kt * 256;
#pragma unroll
    for (int pp = 0; pp < 4; pp++) {
      g2l16(gA[pp] + kb, Ad + pp * 512);
      g2l16(gB[pp] + kb, Bd + pp * 512);
    }
    __syncthreads();
#pragma unroll
    for (int ks = 0; ks < 4; ks++) {
      bf16x8 af[2], bfr[2];
#pragma unroll
      for (int i = 0; i < 2; i++) {
        int ra = wm + i * 16 + l15;
        af[i] = *(const bf16x8*)(lds + ra * 128 +
                                 (((ks * 4 + quad) ^ (ra & 7)) << 3));
        int rb = wn + i * 16 + l15;
        bfr[i] = *(const bf16x8*)(lds + 8192 + rb * 128 +
                                  (((ks * 4 + quad) ^ (rb & 7)) << 3));
      }
#pragma unroll
      for (int i = 0; i < 2; i++)
#pragma unroll
        for (int j = 0; j < 2; j++) acc[i][j] = MFMA(af[i], bfr[j], acc[i][j]);
    }
    __syncthreads();
  }

  float* s4 = (float*)lds + wave * 1024;
#pragma unroll
  for (int i = 0; i < 2; i++)
#pragma unroll
    for (int j = 0; j < 2; j++)
#pragma unroll
      for (int reg = 0; reg < 4; reg++)
        s4[(i * 16 + quad * 4 + reg) * 32 + j * 16 + l15] = acc[i][j][reg];
  __syncthreads();
#pragma unroll
  for (int pp = 0; pp < 4; pp++) {
    int row = pp * 8 + (lane >> 3);
    int c4 = (lane & 7) * 4;
    floatx4 v = *(const floatx4*)&s4[row * 32 + c4];
    size_t goff = (size_t)(m0 + wm + row) * N + n0 + wn + c4;
    floatx4 rv = *(const floatx4*)(resid + goff);
    floatx4 bv = *(const floatx4*)(bias + n0 + wn + c4);
    *(floatx4*)(outF + goff) = v + rv + bv;
  }
}

// ---------------------------------------------------------------------------
// Flash v3: barrier-free wave-private pipeline.
// Block 256 thr / 4 waves; grid (32 qtiles, 24 bh).  kv-tile 64; wave w owns
// s-slice [kv*64 + w*16, +16).  Per-wave LDS (17 KB): K dbuf 2x[16s][64d],
// V 4 strips [64d][16s] (dbuf x pair-parity), P [64][40].  PV per iter-pair
// (s=32).  One s_waitcnt vmcnt(4) per iter; no __syncthreads until epilogue.
// ---------------------------------------------------------------------------
__global__ __launch_bounds__(256, 2) void k_flash(
    const bf16_t* __restrict__ qh, const bf16_t* __restrict__ kh,
    const bf16_t* __restrict__ vt, const float* __restrict__ ab,
    bf16_t* __restrict__ attnA) {
  __shared__ bf16_t sm[35328];  // 4 x 8704 (per-wave) + 512 (l_red, fp32[4][64])

  const int tid = threadIdx.x, lane = tid & 63, wave = tid >> 6;
  const int quad = lane >> 4, l15 = lane & 15;
  const int qtile = blockIdx.x, bh = blockIdx.y;
  const int h = bh % 12, bq = bh / 12;
  const int myv = qtile >> 1;

  bf16_t* wb = sm + wave * 8704;
  bf16_t* Kb0 = wb;            // [2][1024]
  bf16_t* Vs = wb + 2048;      // [2 buf][2 parity][1024]
  bf16_t* Pb = wb + 6144;      // [64][40]

  const bf16_t* Qg = qh + ((size_t)bh * 2048 + qtile * 64) * 64;
  const bf16_t* Kg = kh + ((size_t)bh * 2048 + wave * 16) * 64;

  // K DMA sources: instr i (0,1): lane -> row s=i*8+(lane>>3), chunk lane&7,
  // source chunk xor-swizzled by (s&7).  Advance 8192 B per kv.
  const char* gK[2];
#pragma unroll
  for (int i = 0; i < 2; i++) {
    int sl = i * 8 + (lane >> 3);
    int cs = (lane & 7) ^ (sl & 7);
    gK[i] = (const char*)(Kg + sl * 64 + cs * 8);
  }
  // V DMA sources: instr i: lane -> d=i*32+(lane>>1), half lane&1, source
  // half xor ((d>>2)&1).  Advance 128 B per kv.
  const char* gV[2];
#pragma unroll
  for (int i = 0; i < 2; i++) {
    int d = i * 32 + (lane >> 1);
    int hs = (lane & 1) ^ ((d >> 2) & 1);
    gV[i] = (const char*)(vt + ((size_t)(bh * 64 + d)) * 2048 + wave * 16 + hs * 8);
  }

  // Q in registers: A-frag per (mt, ks)
  bf16x8 qf[4][2];
#pragma unroll
  for (int mt = 0; mt < 4; mt++)
#pragma unroll
    for (int ks = 0; ks < 2; ks++)
      qf[mt][ks] = *(const bf16x8*)(Qg + (size_t)(mt * 16 + l15) * 64 +
                                    ks * 32 + quad * 8);

  // K-frag read offsets (within 1024-elem buf): row l15, chunk swizzled
  int offKr[2];
#pragma unroll
  for (int ks = 0; ks < 2; ks++)
    offKr[ks] = l15 * 64 + ((((ks << 2) + quad) ^ (l15 & 7)) << 3);
  // V-frag read offsets (within 2048-elem buf pair): strip = quad>>1
  int offV[4];
#pragma unroll
  for (int nt = 0; nt < 4; nt++) {
    int d = nt * 16 + l15;
    offV[nt] = (quad >> 1) * 1024 + d * 16 +
               (((quad & 1) ^ ((d >> 2) & 1)) << 3);
  }

  const floatx4 z4 = {0.f, 0.f, 0.f, 0.f};
  floatx4 oacc[4][4];
  float l_lane[4][4];
#pragma unroll
  for (int mt = 0; mt < 4; mt++)
#pragma unroll
    for (int nt = 0; nt < 4; nt++) oacc[mt][nt] = z4;
#pragma unroll
  for (int mt = 0; mt < 4; mt++)
#pragma unroll
    for (int r = 0; r < 4; r++) l_lane[mt][r] = 0.f;

  const float bc_same = ab[h * 2] * LOG2E;
  const float bc_diff = ab[h * 2 + 1] * LOG2E;

  // prologue: K(0) -> buf0, V(0) -> (buf0, parity0)
  g2l16(gK[0], Kb0);
  g2l16(gK[1], Kb0 + 512);
  g2l16(gV[0], Vs);
  g2l16(gV[1], Vs + 512);

  for (int kv = 0; kv < 32; kv++) {
    const int nkv = (kv + 1) & 31;  // wraparound -> uniform issue count
    {
      const size_t kbK = (size_t)nkv * 8192, kbV = (size_t)nkv * 128;
      bf16_t* Kd = Kb0 + (nkv & 1) * 1024;
      bf16_t* Vd = Vs + ((((nkv >> 1) & 1) << 1) + (nkv & 1)) * 1024;
      g2l16(gK[0] + kbK, Kd);
      g2l16(gK[1] + kbK, Kd + 512);
      g2l16(gV[0] + kbV, Vd);
      g2l16(gV[1] + kbV, Vd + 512);
    }
    wait_vm4();  // drains K(kv)+V(kv); leaves the 4 just-issued in flight

    const bf16_t* Kc = Kb0 + (kv & 1) * 1024;
    floatx4 sacc[4] = {z4, z4, z4, z4};
#pragma unroll
    for (int ks = 0; ks < 2; ks++) {
      const bf16x8 kf = *(const bf16x8*)(Kc + offKr[ks]);
#pragma unroll
      for (int mt = 0; mt < 4; mt++)
        sacc[mt] = MFMA(qf[mt][ks], kf, sacc[mt]);
    }

    const float bc = ((kv >> 1) == myv) ? bc_same : bc_diff;
    const int pw = (kv & 1) * 16 + l15;
#pragma unroll
    for (int mt = 0; mt < 4; mt++)
#pragma unroll
      for (int reg = 0; reg < 4; reg++) {
        float pv = exp2f(sacc[mt][reg] + bc);
        l_lane[mt][reg] += pv;
        Pb[(mt * 16 + quad * 4 + reg) * 40 + pw] = f2bf(pv);
      }

    if (kv & 1) {  // pair complete -> PV over s=32
      lds_fence();
      bf16x8 pf[4];
#pragma unroll
      for (int mt = 0; mt < 4; mt++)
        pf[mt] = *(const bf16x8*)(Pb + (mt * 16 + l15) * 40 + quad * 8);
      const int vb = ((kv >> 1) & 1) * 2048;
#pragma unroll
      for (int nt = 0; nt < 4; nt++) {
        const bf16x8 vf = *(const bf16x8*)(Vs + vb + offV[nt]);
#pragma unroll
        for (int mt = 0; mt < 4; mt++)
          oacc[mt][nt] = MFMA(pf[mt], vf, oacc[mt][nt]);
      }
    }
  }

  // ---- epilogue: cross-wave l and O reduction ----
#pragma unroll
  for (int mt = 0; mt < 4; mt++)
#pragma unroll
    for (int reg = 0; reg < 4; reg++) {
      float v = l_lane[mt][reg];
      v += __shfl_xor(v, 1);
      v += __shfl_xor(v, 2);
      v += __shfl_xor(v, 4);
      v += __shfl_xor(v, 8);
      l_lane[mt][reg] = v;
    }
  float* lred = (float*)(sm + 34816);  // [4][64]
  if (l15 == 0) {
#pragma unroll
    for (int mt = 0; mt < 4; mt++)
#pragma unroll
      for (int reg = 0; reg < 4; reg++)
        lred[wave * 64 + mt * 16 + quad * 4 + reg] = l_lane[mt][reg];
  }
  // partial O (bf16) into wave's own region [64][64]
#pragma unroll
  for (int mt = 0; mt < 4; mt++)
#pragma unroll
    for (int nt = 0; nt < 4; nt++)
#pragma unroll
      for (int reg = 0; reg < 4; reg++)
        wb[(mt * 16 + quad * 4 + reg) * 64 + nt * 16 + l15] =
            f2bf(oacc[mt][nt][reg]);
  __syncthreads();

  const int q = tid >> 2, dg = (tid & 3) * 16;
  const float inv =
      1.0f / (lred[q] + lred[64 + q] + lred[128 + q] + lred[192 + q]);
  float o[16];
#pragma unroll
  for (int j = 0; j < 16; j++) o[j] = 0.f;
#pragma unroll
  for (int w = 0; w < 4; w++) {
    const bf16x8 a = *(const bf16x8*)(sm + w * 8704 + q * 64 + dg);
    const bf16x8 b = *(const bf16x8*)(sm + w * 8704 + q * 64 + dg + 8);
#pragma unroll
    for (int j = 0; j < 8; j++) {
      o[j] += (float)a[j];
      o[8 + j] += (float)b[j];
    }
  }
  bf16x8 r0, r1;
#pragma unroll
  for (int j = 0; j < 8; j++) {
    r0[j] = f2bf(o[j] * inv);
    r1[j] = f2bf(o[8 + j] * inv);
  }
  bf16_t* outp =
      attnA + ((size_t)(bq * 2048 + qtile * 64 + q)) * 768 + h * 64 + dg;
  *(bf16x8*)outp = r0;
  *(bf16x8*)(outp + 8) = r1;
}

// ---------------------------------------------------------------------------
extern "C" void kernel_launch(void* const* d_in, const int* in_sizes, int n_in,
                              void* d_out, int out_size, void* d_ws,
                              size_t ws_size, hipStream_t stream) {
  const float* hs  = (const float*)d_in[0];
  const float* wq  = (const float*)d_in[1];
  const float* bq  = (const float*)d_in[2];
  const float* wk  = (const float*)d_in[3];
  const float* bk  = (const float*)d_in[4];
  const float* wv  = (const float*)d_in[5];
  const float* bv  = (const float*)d_in[6];
  const float* wo  = (const float*)d_in[7];
  const float* bo  = (const float*)d_in[8];
  const float* ab  = (const float*)d_in[9];
  const float* g1  = (const float*)d_in[10];
  const float* be1 = (const float*)d_in[11];
  const float* g3  = (const float*)d_in[12];
  const float* be3 = (const float*)d_in[13];
  const float* w1  = (const float*)d_in[14];
  const float* b1  = (const float*)d_in[15];
  const float* w2  = (const float*)d_in[16];
  const float* b2  = (const float*)d_in[17];

  char* ws = (char*)d_ws;
  size_t off = 0;
  auto alloc = [&](size_t bytes) -> void* {
    void* p = ws + off;
    off += (bytes + 255) & ~(size_t)255;
    return p;
  };
  bf16_t* wqkvT = (bf16_t*)alloc((size_t)2304 * 768 * 2);
  bf16_t* woT   = (bf16_t*)alloc((size_t)768 * 768 * 2);
  bf16_t* w1T   = (bf16_t*)alloc((size_t)3072 * 768 * 2);
  bf16_t* w2T   = (bf16_t*)alloc((size_t)768 * 3072 * 2);
  bf16_t* ni    = (bf16_t*)alloc((size_t)4096 * 768 * 2);
  bf16_t* qhB   = (bf16_t*)alloc((size_t)24 * 2048 * 64 * 2);
  bf16_t* khB   = (bf16_t*)alloc((size_t)24 * 2048 * 64 * 2);
  bf16_t* vtB   = (bf16_t*)alloc((size_t)24 * 64 * 2048 * 2);
  bf16_t* attnA = (bf16_t*)alloc((size_t)4096 * 768 * 2);
  float*  resid1 = (float*)alloc((size_t)4096 * 768 * 4);
  bf16_t* ffn1o = qhB;  // overlay: q/k/v/attn region dead by FFN1 time

  // prep: all transposes + LN1, one dispatch
  PrepP pp = {wq, wk, wv, wo, w1, w2, wqkvT, woT, w1T, w2T, hs, g1, be1, ni};
  k_prep<<<11008, 256, 0, stream>>>(pp);

  // QKV (fused, N=2304): bias, q*0.125*log2e, p-RoPE, head-layout scatter
  GemmP gqkv = {ni, wqkvT, 4096, 2304, 768, 0,
                bq, bk, bv, nullptr, qhB, khB, vtB};
  k_gemm<<<dim3(18, 32), 256, 0, stream>>>(gqkv);

  // flash attention v3 (barrier-free wave-private)
  k_flash<<<dim3(32, 24), 256, 0, stream>>>(qhB, khB, vtB, ab, attnA);

  // attn @ wo + bo + residual(hidden) -> resid1 (fp32)
  k_gemm64<<<dim3(12, 64), 256, 0, stream>>>(attnA, woT, 768, 768, bo, hs,
                                             resid1);

  // LN3
  k_layernorm<<<4096, 256, 0, stream>>>(resid1, g3, be3, ni);

  // FFN1 + exact GELU -> bf16
  GemmP gf1 = {ni, w1T, 4096, 3072, 768, 2,
               b1, nullptr, nullptr, nullptr, ffn1o, nullptr, nullptr};
  k_gemm<<<dim3(24, 32), 256, 0, stream>>>(gf1);

  // FFN2 + b2 + residual -> d_out (fp32 [4096][768])
  k_gemm64<<<dim3(12, 64), 256, 0, stream>>>(ffn1o, w2T, 768, 3072, b2,
                                             resid1, (float*)d_out);
}